// Round 5
// baseline (50.997 us; speedup 1.0000x reference)
//
#include <hip/hip_runtime.h>

#pragma clang fp contract(off)

#define HH 512
#define WW 640
#define HW (HH * WW)

// Emulate PyPI-numpy (OpenBLAS, AVX2/FMA dispatch) float32 semantics:
//  - np.linalg.inv -> sgesv: getf2 (reciprocal scal, FMA ger) + strsm with
//    OpenBLAS pre-inverted diagonal (reciprocal multiply), column-oriented
//    update order, FMA updates
//  - matmul -> cblas_sgemm per 3x3 slice: k-ascending FMA accumulation from 0
//  - einsum -> AVX2-dispatched sum_of_products scalar tail with gcc
//    fp-contract: acc = rnd(M0*x); acc = fma(M1,y,acc); acc = acc + M2
//  - elementwise ufuncs (mul/add/div) -> separately rounded, no FMA
__device__ void precompute_batch(const float* __restrict__ K9,
                                 const float* __restrict__ R9,
                                 const float* __restrict__ t3,
                                 float* __restrict__ Mout,   // 9
                                 float* __restrict__ Wvout)  // 3
{
#pragma clang fp contract(off)
    float K[3][3], R[3][3], t[3];
    #pragma unroll
    for (int i = 0; i < 3; ++i) {
        #pragma unroll
        for (int j = 0; j < 3; ++j) { K[i][j] = K9[i * 3 + j]; R[i][j] = R9[i * 3 + j]; }
        t[i] = t3[i];
    }

    // ---- sgetf2: LU w/ partial pivoting, reciprocal scal, FMA ger ----
    float A[3][3];
    #pragma unroll
    for (int i = 0; i < 3; ++i)
        #pragma unroll
        for (int j = 0; j < 3; ++j) A[i][j] = K[i][j];
    int piv[3];
    for (int j = 0; j < 3; ++j) {
        int p = j;
        for (int i = j + 1; i < 3; ++i)
            if (__builtin_fabsf(A[i][j]) > __builtin_fabsf(A[p][j])) p = i;
        piv[j] = p;
        if (p != j) {
            for (int k = 0; k < 3; ++k) { float tmp = A[j][k]; A[j][k] = A[p][k]; A[p][k] = tmp; }
        }
        const float rinv = 1.0f / A[j][j];              // sscal by reciprocal
        for (int i = j + 1; i < 3; ++i) A[i][j] = A[i][j] * rinv;
        for (int k = j + 1; k < 3; ++k)                  // sger: FMA update
            for (int i = j + 1; i < 3; ++i)
                A[i][k] = __builtin_fmaf(-A[i][j], A[j][k], A[i][k]);
    }
    const float invd[3] = {1.0f / A[0][0], 1.0f / A[1][1], 1.0f / A[2][2]};

    // ---- sgetrs (B = I): laswp + column-oriented trsm, recip diag, FMA ----
    float Ki[3][3];
    for (int c = 0; c < 3; ++c) {
        float b[3] = {0.0f, 0.0f, 0.0f};
        b[c] = 1.0f;
        for (int j = 0; j < 3; ++j)
            if (piv[j] != j) { float tmp = b[j]; b[j] = b[piv[j]]; b[piv[j]] = tmp; }
        // forward (L, unit): k ascending, update rows below (FMA)
        for (int k = 0; k < 3; ++k)
            for (int i = k + 1; i < 3; ++i)
                b[i] = __builtin_fmaf(-A[i][k], b[k], b[i]);
        // backward (U, non-unit): k descending, x_k = b_k * invd_k (OpenBLAS
        // pre-inverted diagonal), then update rows above (FMA)
        for (int k = 2; k >= 0; --k) {
            b[k] = b[k] * invd[k];
            for (int i = 0; i < k; ++i)
                b[i] = __builtin_fmaf(-A[i][k], b[k], b[i]);
        }
        for (int i = 0; i < 3; ++i) Ki[i][c] = b[i];
    }

    // ---- T = K @ R^T  (sgemm: FMA, k ascending, from 0) ----
    float T[3][3];
    #pragma unroll
    for (int i = 0; i < 3; ++i)
        #pragma unroll
        for (int j = 0; j < 3; ++j) {
            float acc = 0.0f;
            #pragma unroll
            for (int k = 0; k < 3; ++k) acc = __builtin_fmaf(K[i][k], R[j][k], acc);
            T[i][j] = acc;
        }

    // ---- Wv = T @ (-t)  (negate ufunc exact, then sgemm FMA chain) ----
    const float nt[3] = {-t[0], -t[1], -t[2]};
    #pragma unroll
    for (int i = 0; i < 3; ++i) {
        float acc = 0.0f;
        #pragma unroll
        for (int k = 0; k < 3; ++k) acc = __builtin_fmaf(T[i][k], nt[k], acc);
        Wvout[i] = acc;
    }

    // ---- M = T @ Ki  (sgemm FMA chain) ----
    #pragma unroll
    for (int i = 0; i < 3; ++i)
        #pragma unroll
        for (int j = 0; j < 3; ++j) {
            float acc = 0.0f;
            #pragma unroll
            for (int k = 0; k < 3; ++k) acc = __builtin_fmaf(T[i][k], Ki[k][j], acc);
            Mout[i * 3 + j] = acc;
        }
}

__global__ __launch_bounds__(256) void flow_from_depth_kernel(
    const float* __restrict__ dep, const float* __restrict__ msk,
    const float* __restrict__ tvec, const float* __restrict__ rot,
    const float* __restrict__ kmat, float* __restrict__ out)
{
#pragma clang fp contract(off)
    __shared__ float sM[9];
    __shared__ float sWv[3];
    const int b = blockIdx.y;

    if (threadIdx.x == 0)
        precompute_batch(kmat + b * 9, rot + b * 9, tvec + b * 3, sM, sWv);
    __syncthreads();

    const float M00 = sM[0], M01 = sM[1], M02 = sM[2];
    const float M10 = sM[3], M11 = sM[4], M12 = sM[5];
    const float M20 = sM[6], M21 = sM[7], M22 = sM[8];
    const float W0 = sWv[0], W1 = sWv[1], W2 = sWv[2];

    const int i4  = blockIdx.x * blockDim.x + threadIdx.x;  // 0 .. HW/4-1
    const int pix = i4 * 4;
    const int y   = pix / WW;
    const int x0  = pix - y * WW;        // W % 4 == 0 -> all 4 pixels share row y
    const float fy = (float)y;

    const float4 dv = ((const float4*)dep)[b * (HW / 4) + i4];
    const float4 mv = ((const float4*)msk)[b * (HW / 4) + i4];

    const float dvals[4] = {dv.x, dv.y, dv.z, dv.w};
    const float mvals[4] = {mv.x, mv.y, mv.z, mv.w};
    float uu[4], vv[4];

    #pragma unroll
    for (int j = 0; j < 4; ++j) {
        const float fx = (float)(x0 + j);
        // einsum AVX2 sop: acc = rnd(M0*x); acc = fma(M1,y,acc); acc += M2
        float i0 = M00 * fx; i0 = __builtin_fmaf(M01, fy, i0); i0 = i0 + M02;
        float i1 = M10 * fx; i1 = __builtin_fmaf(M11, fy, i1); i1 = i1 + M12;
        float i2 = M20 * fx; i2 = __builtin_fmaf(M21, fy, i2); i2 = i2 + M22;
        const float d_ = dvals[j];
        const float m_ = mvals[j];
        // num = Wv + d*inter : separate ufuncs (rounded mul, then rounded add)
        const float p0 = d_ * i0;
        const float p1 = d_ * i1;
        const float p2 = d_ * i2;
        const float n0 = W0 + p0;
        const float n1 = W1 + p1;
        const float n2 = W2 + p2;
        const float om = 1.0f - m_;
        const float q0 = 1e30f * om;
        const float q1 = m_ * n2;
        const float depth2 = q0 + q1;
        const float u2 = n0 / depth2;       // IEEE f32 div
        const float v2 = n1 / depth2;
        uu[j] = (u2 - fx) / 640.0f;
        vv[j] = (v2 - fy) / 512.0f;
    }

    const int obase = b * (2 * HW / 4);
    ((float4*)out)[obase + i4]          = make_float4(uu[0], uu[1], uu[2], uu[3]);
    ((float4*)out)[obase + HW / 4 + i4] = make_float4(vv[0], vv[1], vv[2], vv[3]);
}

extern "C" void kernel_launch(void* const* d_in, const int* in_sizes, int n_in,
                              void* d_out, int out_size, void* d_ws, size_t ws_size,
                              hipStream_t stream) {
    const float* dep = (const float*)d_in[0];
    const float* msk = (const float*)d_in[1];
    const float* tv  = (const float*)d_in[2];
    const float* rm  = (const float*)d_in[3];
    const float* km  = (const float*)d_in[4];
    float* out = (float*)d_out;

    const int B = in_sizes[3] / 9;         // rotation matrices: B*3*3
    dim3 grid(HW / (4 * 256), B);
    flow_from_depth_kernel<<<grid, 256, 0, stream>>>(dep, msk, tv, rm, km, out);
}

// Round 6
// 35.489 us; speedup vs baseline: 1.4370x; 1.4370x over previous
//
#include <hip/hip_runtime.h>

#pragma clang fp contract(off)

#define HH 512
#define WW 640
#define HW (HH * WW)
#define NV4 (HW / 4)          // 81920 float4 per image
#define V4_PER_ITER 20480     // 80 blocks * 256 threads
#define NITER 4               // 4 float4 per thread = 16 pixels

// Emulate PyPI-numpy (OpenBLAS, AVX2/FMA dispatch) float32 semantics:
//  - np.linalg.inv -> sgesv: getf2 (reciprocal scal, FMA ger) + strsm with
//    OpenBLAS pre-inverted diagonal (reciprocal multiply), column-oriented
//    update order, FMA updates
//  - matmul -> cblas_sgemm per 3x3 slice: k-ascending FMA accumulation from 0
//  - einsum -> AVX2-dispatched sum_of_products scalar tail with gcc
//    fp-contract: acc = rnd(M0*x); acc = fma(M1,y,acc); acc = acc + M2
//  - elementwise ufuncs (mul/add/div) -> separately rounded, no FMA
// VERIFIED bit-exact (absmax 0.0) in round 5 — do not alter any rounding.
__device__ void precompute_batch(const float* __restrict__ K9,
                                 const float* __restrict__ R9,
                                 const float* __restrict__ t3,
                                 float* __restrict__ Mout,   // 9
                                 float* __restrict__ Wvout)  // 3
{
#pragma clang fp contract(off)
    float K[3][3], R[3][3], t[3];
    #pragma unroll
    for (int i = 0; i < 3; ++i) {
        #pragma unroll
        for (int j = 0; j < 3; ++j) { K[i][j] = K9[i * 3 + j]; R[i][j] = R9[i * 3 + j]; }
        t[i] = t3[i];
    }

    // ---- sgetf2: LU w/ partial pivoting, reciprocal scal, FMA ger ----
    float A[3][3];
    #pragma unroll
    for (int i = 0; i < 3; ++i)
        #pragma unroll
        for (int j = 0; j < 3; ++j) A[i][j] = K[i][j];
    int piv[3];
    for (int j = 0; j < 3; ++j) {
        int p = j;
        for (int i = j + 1; i < 3; ++i)
            if (__builtin_fabsf(A[i][j]) > __builtin_fabsf(A[p][j])) p = i;
        piv[j] = p;
        if (p != j) {
            for (int k = 0; k < 3; ++k) { float tmp = A[j][k]; A[j][k] = A[p][k]; A[p][k] = tmp; }
        }
        const float rinv = 1.0f / A[j][j];              // sscal by reciprocal
        for (int i = j + 1; i < 3; ++i) A[i][j] = A[i][j] * rinv;
        for (int k = j + 1; k < 3; ++k)                  // sger: FMA update
            for (int i = j + 1; i < 3; ++i)
                A[i][k] = __builtin_fmaf(-A[i][j], A[j][k], A[i][k]);
    }
    const float invd[3] = {1.0f / A[0][0], 1.0f / A[1][1], 1.0f / A[2][2]};

    // ---- sgetrs (B = I): laswp + column-oriented trsm, recip diag, FMA ----
    float Ki[3][3];
    for (int c = 0; c < 3; ++c) {
        float b[3] = {0.0f, 0.0f, 0.0f};
        b[c] = 1.0f;
        for (int j = 0; j < 3; ++j)
            if (piv[j] != j) { float tmp = b[j]; b[j] = b[piv[j]]; b[piv[j]] = tmp; }
        // forward (L, unit): k ascending, update rows below (FMA)
        for (int k = 0; k < 3; ++k)
            for (int i = k + 1; i < 3; ++i)
                b[i] = __builtin_fmaf(-A[i][k], b[k], b[i]);
        // backward (U, non-unit): k descending, x_k = b_k * invd_k, FMA updates
        for (int k = 2; k >= 0; --k) {
            b[k] = b[k] * invd[k];
            for (int i = 0; i < k; ++i)
                b[i] = __builtin_fmaf(-A[i][k], b[k], b[i]);
        }
        for (int i = 0; i < 3; ++i) Ki[i][c] = b[i];
    }

    // ---- T = K @ R^T  (sgemm: FMA, k ascending, from 0) ----
    float T[3][3];
    #pragma unroll
    for (int i = 0; i < 3; ++i)
        #pragma unroll
        for (int j = 0; j < 3; ++j) {
            float acc = 0.0f;
            #pragma unroll
            for (int k = 0; k < 3; ++k) acc = __builtin_fmaf(K[i][k], R[j][k], acc);
            T[i][j] = acc;
        }

    // ---- Wv = T @ (-t)  (negate exact, then sgemm FMA chain) ----
    const float nt[3] = {-t[0], -t[1], -t[2]};
    #pragma unroll
    for (int i = 0; i < 3; ++i) {
        float acc = 0.0f;
        #pragma unroll
        for (int k = 0; k < 3; ++k) acc = __builtin_fmaf(T[i][k], nt[k], acc);
        Wvout[i] = acc;
    }

    // ---- M = T @ Ki  (sgemm FMA chain) ----
    #pragma unroll
    for (int i = 0; i < 3; ++i)
        #pragma unroll
        for (int j = 0; j < 3; ++j) {
            float acc = 0.0f;
            #pragma unroll
            for (int k = 0; k < 3; ++k) acc = __builtin_fmaf(T[i][k], Ki[k][j], acc);
            Mout[i * 3 + j] = acc;
        }
}

// One lane per batch: write M (9) + Wv (3) into ws[b*16 + 0..11]
__global__ void precompute_kernel(const float* __restrict__ tvec,
                                  const float* __restrict__ rot,
                                  const float* __restrict__ kmat,
                                  float* __restrict__ ws, int B)
{
    const int b = blockIdx.x * blockDim.x + threadIdx.x;
    if (b >= B) return;
    float M[9], Wv[3];
    precompute_batch(kmat + b * 9, rot + b * 9, tvec + b * 3, M, Wv);
    float* w = ws + b * 16;
    #pragma unroll
    for (int i = 0; i < 9; ++i) w[i] = M[i];
    #pragma unroll
    for (int i = 0; i < 3; ++i) w[9 + i] = Wv[i];
}

__global__ __launch_bounds__(256) void flow_main_kernel(
    const float* __restrict__ dep, const float* __restrict__ msk,
    const float* __restrict__ ws, float* __restrict__ out)
{
#pragma clang fp contract(off)
    const int b = blockIdx.y;
    const float* __restrict__ w = ws + b * 16;   // uniform -> scalar loads
    const float M00 = w[0], M01 = w[1], M02 = w[2];
    const float M10 = w[3], M11 = w[4], M12 = w[5];
    const float M20 = w[6], M21 = w[7], M22 = w[8];
    const float W0 = w[9], W1 = w[10], W2 = w[11];

    const int t = blockIdx.x * 256 + threadIdx.x;      // 0 .. 20479
    const int ibase = b * NV4;
    const int obase = b * (2 * NV4);

    #pragma unroll
    for (int k = 0; k < NITER; ++k) {
        const int i4  = t + k * V4_PER_ITER;
        const int pix = i4 * 4;
        const int y   = pix / WW;
        const int x0  = pix - y * WW;      // W % 4 == 0 -> row-uniform quad
        const float fy = (float)y;

        const float4 dv = ((const float4*)dep)[ibase + i4];
        const float4 mv = ((const float4*)msk)[ibase + i4];
        const float dvals[4] = {dv.x, dv.y, dv.z, dv.w};
        const float mvals[4] = {mv.x, mv.y, mv.z, mv.w};
        float uu[4], vv[4];

        #pragma unroll
        for (int j = 0; j < 4; ++j) {
            const float fx = (float)(x0 + j);
            // einsum AVX2 sop: acc = rnd(M0*x); acc = fma(M1,y,acc); acc += M2
            float i0 = M00 * fx; i0 = __builtin_fmaf(M01, fy, i0); i0 = i0 + M02;
            float i1 = M10 * fx; i1 = __builtin_fmaf(M11, fy, i1); i1 = i1 + M12;
            float i2 = M20 * fx; i2 = __builtin_fmaf(M21, fy, i2); i2 = i2 + M22;
            const float d_ = dvals[j];
            const float m_ = mvals[j];
            // num = Wv + d*inter : separate ufuncs (rounded mul, rounded add)
            const float p0 = d_ * i0;
            const float p1 = d_ * i1;
            const float p2 = d_ * i2;
            const float n0 = W0 + p0;
            const float n1 = W1 + p1;
            const float n2 = W2 + p2;
            const float om = 1.0f - m_;
            const float q0 = 1e30f * om;
            const float q1 = m_ * n2;
            const float depth2 = q0 + q1;
            const float u2 = n0 / depth2;   // IEEE f32 div (pole-critical)
            const float v2 = n1 / depth2;
            uu[j] = (u2 - fx) / 640.0f;
            vv[j] = (v2 - fy) / 512.0f;
        }

        ((float4*)out)[obase + i4]       = make_float4(uu[0], uu[1], uu[2], uu[3]);
        ((float4*)out)[obase + NV4 + i4] = make_float4(vv[0], vv[1], vv[2], vv[3]);
    }
}

extern "C" void kernel_launch(void* const* d_in, const int* in_sizes, int n_in,
                              void* d_out, int out_size, void* d_ws, size_t ws_size,
                              hipStream_t stream) {
    const float* dep = (const float*)d_in[0];
    const float* msk = (const float*)d_in[1];
    const float* tv  = (const float*)d_in[2];
    const float* rm  = (const float*)d_in[3];
    const float* km  = (const float*)d_in[4];
    float* out = (float*)d_out;
    float* ws  = (float*)d_ws;

    const int B = in_sizes[3] / 9;         // rotation matrices: B*3*3

    precompute_kernel<<<1, 64, 0, stream>>>(tv, rm, km, ws, B);

    dim3 grid(NV4 / (NITER * 256), B);     // (80, 32)
    flow_main_kernel<<<grid, 256, 0, stream>>>(dep, msk, ws, out);
}

// Round 7
// 34.631 us; speedup vs baseline: 1.4726x; 1.0248x over previous
//
#include <hip/hip_runtime.h>

#pragma clang fp contract(off)

#define HH 512
#define WW 640
#define HW (HH * WW)
#define NV4 (HW / 4)          // 81920 float4 per image
#define NITER 2               // 2 float4 per thread = 8 pixels
#define V4_PER_ITER (NV4 / NITER)   // 40960 = 160 blocks * 256 threads

// Emulate PyPI-numpy (OpenBLAS, AVX2/FMA dispatch) float32 semantics:
//  - np.linalg.inv -> sgesv: getf2 (reciprocal scal, FMA ger) + strsm with
//    OpenBLAS pre-inverted diagonal (reciprocal multiply), FMA updates
//  - matmul -> cblas_sgemm per 3x3 slice: k-ascending FMA accumulation from 0
//  - einsum -> AVX2 sum_of_products with gcc fp-contract:
//    acc = rnd(M0*x); acc = fma(M1,y,acc); acc = acc + M2
//  - elementwise ufuncs (mul/add/div) -> separately rounded, no FMA
// VERIFIED bit-exact (absmax 0.0) in rounds 5/6 — do not alter any rounding.
__device__ void precompute_batch(const float* __restrict__ K9,
                                 const float* __restrict__ R9,
                                 const float* __restrict__ t3,
                                 float* __restrict__ Mout,   // 9
                                 float* __restrict__ Wvout)  // 3
{
#pragma clang fp contract(off)
    float K[3][3], R[3][3], t[3];
    #pragma unroll
    for (int i = 0; i < 3; ++i) {
        #pragma unroll
        for (int j = 0; j < 3; ++j) { K[i][j] = K9[i * 3 + j]; R[i][j] = R9[i * 3 + j]; }
        t[i] = t3[i];
    }

    // ---- sgetf2: LU w/ partial pivoting, reciprocal scal, FMA ger ----
    float A[3][3];
    #pragma unroll
    for (int i = 0; i < 3; ++i)
        #pragma unroll
        for (int j = 0; j < 3; ++j) A[i][j] = K[i][j];
    int piv[3];
    for (int j = 0; j < 3; ++j) {
        int p = j;
        for (int i = j + 1; i < 3; ++i)
            if (__builtin_fabsf(A[i][j]) > __builtin_fabsf(A[p][j])) p = i;
        piv[j] = p;
        if (p != j) {
            for (int k = 0; k < 3; ++k) { float tmp = A[j][k]; A[j][k] = A[p][k]; A[p][k] = tmp; }
        }
        const float rinv = 1.0f / A[j][j];              // sscal by reciprocal
        for (int i = j + 1; i < 3; ++i) A[i][j] = A[i][j] * rinv;
        for (int k = j + 1; k < 3; ++k)                  // sger: FMA update
            for (int i = j + 1; i < 3; ++i)
                A[i][k] = __builtin_fmaf(-A[i][j], A[j][k], A[i][k]);
    }
    const float invd[3] = {1.0f / A[0][0], 1.0f / A[1][1], 1.0f / A[2][2]};

    // ---- sgetrs (B = I): laswp + column-oriented trsm, recip diag, FMA ----
    float Ki[3][3];
    for (int c = 0; c < 3; ++c) {
        float b[3] = {0.0f, 0.0f, 0.0f};
        b[c] = 1.0f;
        for (int j = 0; j < 3; ++j)
            if (piv[j] != j) { float tmp = b[j]; b[j] = b[piv[j]]; b[piv[j]] = tmp; }
        for (int k = 0; k < 3; ++k)
            for (int i = k + 1; i < 3; ++i)
                b[i] = __builtin_fmaf(-A[i][k], b[k], b[i]);
        for (int k = 2; k >= 0; --k) {
            b[k] = b[k] * invd[k];
            for (int i = 0; i < k; ++i)
                b[i] = __builtin_fmaf(-A[i][k], b[k], b[i]);
        }
        for (int i = 0; i < 3; ++i) Ki[i][c] = b[i];
    }

    // ---- T = K @ R^T  (sgemm: FMA, k ascending, from 0) ----
    float T[3][3];
    #pragma unroll
    for (int i = 0; i < 3; ++i)
        #pragma unroll
        for (int j = 0; j < 3; ++j) {
            float acc = 0.0f;
            #pragma unroll
            for (int k = 0; k < 3; ++k) acc = __builtin_fmaf(K[i][k], R[j][k], acc);
            T[i][j] = acc;
        }

    // ---- Wv = T @ (-t) ----
    const float nt[3] = {-t[0], -t[1], -t[2]};
    #pragma unroll
    for (int i = 0; i < 3; ++i) {
        float acc = 0.0f;
        #pragma unroll
        for (int k = 0; k < 3; ++k) acc = __builtin_fmaf(T[i][k], nt[k], acc);
        Wvout[i] = acc;
    }

    // ---- M = T @ Ki ----
    #pragma unroll
    for (int i = 0; i < 3; ++i)
        #pragma unroll
        for (int j = 0; j < 3; ++j) {
            float acc = 0.0f;
            #pragma unroll
            for (int k = 0; k < 3; ++k) acc = __builtin_fmaf(T[i][k], Ki[k][j], acc);
            Mout[i * 3 + j] = acc;
        }
}

// One lane per batch: write M (9) + Wv (3) into ws[b*16 + 0..11]
__global__ void precompute_kernel(const float* __restrict__ tvec,
                                  const float* __restrict__ rot,
                                  const float* __restrict__ kmat,
                                  float* __restrict__ ws, int B)
{
    const int b = blockIdx.x * blockDim.x + threadIdx.x;
    if (b >= B) return;
    float M[9], Wv[3];
    precompute_batch(kmat + b * 9, rot + b * 9, tvec + b * 3, M, Wv);
    float* w = ws + b * 16;
    #pragma unroll
    for (int i = 0; i < 9; ++i) w[i] = M[i];
    #pragma unroll
    for (int i = 0; i < 3; ++i) w[9 + i] = Wv[i];
}

__global__ __launch_bounds__(256) void flow_main_kernel(
    const float* __restrict__ dep, const float* __restrict__ msk,
    const float* __restrict__ ws, float* __restrict__ out)
{
#pragma clang fp contract(off)
    const int b = blockIdx.y;
    const float* __restrict__ w = ws + b * 16;   // uniform -> scalar loads
    const float M00 = w[0], M01 = w[1], M02 = w[2];
    const float M10 = w[3], M11 = w[4], M12 = w[5];
    const float M20 = w[6], M21 = w[7], M22 = w[8];
    const float W0 = w[9], W1 = w[10], W2 = w[11];

    const int t = blockIdx.x * 256 + threadIdx.x;      // 0 .. 40959
    const int ibase = b * NV4;
    const int obase = b * (2 * NV4);

    // ---- phase 1: issue ALL global loads (stay in VGPRs, static indexing) ----
    float4 dv[NITER], mv[NITER];
    #pragma unroll
    for (int k = 0; k < NITER; ++k) {
        const int i4 = t + k * V4_PER_ITER;
        dv[k] = ((const float4*)dep)[ibase + i4];
        mv[k] = ((const float4*)msk)[ibase + i4];
    }

    // ---- phase 2: compute + store per iteration ----
    #pragma unroll
    for (int k = 0; k < NITER; ++k) {
        const int i4  = t + k * V4_PER_ITER;
        const int pix = i4 * 4;
        const int y   = pix / WW;
        const int x0  = pix - y * WW;      // W % 4 == 0 -> row-uniform quad
        const float fy = (float)y;

        const float dvals[4] = {dv[k].x, dv[k].y, dv[k].z, dv[k].w};
        const float mvals[4] = {mv[k].x, mv[k].y, mv[k].z, mv[k].w};
        float uu[4], vv[4];

        #pragma unroll
        for (int j = 0; j < 4; ++j) {
            const float fx = (float)(x0 + j);
            // einsum AVX2 sop: acc = rnd(M0*x); acc = fma(M1,y,acc); acc += M2
            float i0 = M00 * fx; i0 = __builtin_fmaf(M01, fy, i0); i0 = i0 + M02;
            float i1 = M10 * fx; i1 = __builtin_fmaf(M11, fy, i1); i1 = i1 + M12;
            float i2 = M20 * fx; i2 = __builtin_fmaf(M21, fy, i2); i2 = i2 + M22;
            const float d_ = dvals[j];
            const float m_ = mvals[j];
            // num = Wv + d*inter : separate ufuncs (rounded mul, rounded add)
            const float p0 = d_ * i0;
            const float p1 = d_ * i1;
            const float p2 = d_ * i2;
            const float n0 = W0 + p0;
            const float n1 = W1 + p1;
            const float n2 = W2 + p2;
            const float om = 1.0f - m_;
            const float q0 = 1e30f * om;
            const float q1 = m_ * n2;
            const float depth2 = q0 + q1;
            const float u2 = n0 / depth2;   // IEEE f32 div (pole-critical)
            const float v2 = n1 / depth2;
            uu[j] = (u2 - fx) / 640.0f;
            vv[j] = (v2 - fy) / 512.0f;
        }

        ((float4*)out)[obase + i4]       = make_float4(uu[0], uu[1], uu[2], uu[3]);
        ((float4*)out)[obase + NV4 + i4] = make_float4(vv[0], vv[1], vv[2], vv[3]);
    }
}

extern "C" void kernel_launch(void* const* d_in, const int* in_sizes, int n_in,
                              void* d_out, int out_size, void* d_ws, size_t ws_size,
                              hipStream_t stream) {
    const float* dep = (const float*)d_in[0];
    const float* msk = (const float*)d_in[1];
    const float* tv  = (const float*)d_in[2];
    const float* rm  = (const float*)d_in[3];
    const float* km  = (const float*)d_in[4];
    float* out = (float*)d_out;
    float* ws  = (float*)d_ws;

    const int B = in_sizes[3] / 9;         // rotation matrices: B*3*3

    precompute_kernel<<<1, 64, 0, stream>>>(tv, rm, km, ws, B);

    dim3 grid(V4_PER_ITER / 256, B);       // (160, 32)
    flow_main_kernel<<<grid, 256, 0, stream>>>(dep, msk, ws, out);
}